// Round 6
// baseline (2773.418 us; speedup 1.0000x reference)
//
#include <hip/hip_runtime.h>
#include <hip/hip_bf16.h>
#include <stdint.h>

#define N_NODES   100000
#define N_EDGES   3200000
#define IN_FEAT   128
#define OUT_FEAT  128
#define NUM_RELS  16
#define NUM_BASES 8
#define M_PAD     100096      // 782*128 (conv_x padding)
#define NTILE     1563        // ceil(100000/64) dst tiles of 64
#define NB        256         // coarse hist/place block count
#define NSEG      (NTILE * NUM_RELS)   // 25008

using short8 = __attribute__((ext_vector_type(8))) short;
using v4f    = __attribute__((ext_vector_type(4))) float;

__device__ inline unsigned short f2bf_rne(float f) {
    __hip_bfloat16 h = __float2bfloat16(f);
    return *reinterpret_cast<unsigned short*>(&h);
}
__device__ inline float bf2f(unsigned short u) {
    union { uint32_t i; float f; } x;
    x.i = ((uint32_t)u) << 16;
    return x.f;
}

// ---------------------------------------------------------------------------
// x fp32 -> bf16, zero-padded to M_PAD rows
// ---------------------------------------------------------------------------
__global__ void conv_x(const float* __restrict__ x, unsigned short* __restrict__ xb) {
    int id = blockIdx.x * 256 + threadIdx.x;
    int base = id * 4;
    ushort4 o;
    if (base < N_NODES * IN_FEAT) {
        const float4 v = reinterpret_cast<const float4*>(x)[id];
        o.x = f2bf_rne(v.x); o.y = f2bf_rne(v.y);
        o.z = f2bf_rne(v.z); o.w = f2bf_rne(v.w);
    } else {
        o.x = o.y = o.z = o.w = 0;
    }
    reinterpret_cast<ushort4*>(xb)[id] = o;
}

// ---------------------------------------------------------------------------
// Bt[n][k] = sum_b w_comp[r][b] * weight[b][k][o], n = r*128+o (bf16)
// i.e. per-rel W^T: row (r,o), col k=i. B-operand layout for MFMA.
// ---------------------------------------------------------------------------
__global__ void build_w(const float* __restrict__ weight,
                        const float* __restrict__ w_comp,
                        unsigned short* __restrict__ Bt) {
    int id = blockIdx.x * 256 + threadIdx.x;
    int n = id >> 7;
    int k = id & 127;
    int r = n >> 7;
    int o = n & 127;
    float acc = 0.f;
#pragma unroll
    for (int b = 0; b < NUM_BASES; ++b)
        acc += w_comp[r * NUM_BASES + b] * weight[(b * IN_FEAT + k) * OUT_FEAT + o];
    Bt[id] = f2bf_rne(acc);
}

// ---------------------------------------------------------------------------
// Sort stage 1: coarse bucket = dst>>6 (one bucket per 64-node dst tile).
// Per-block LDS histogram -> histG[bucket*NB + block]  (no global atomics)
// ---------------------------------------------------------------------------
__global__ __launch_bounds__(1024) void coarse_hist(const int* __restrict__ dst,
                                                    int* __restrict__ histG) {
    __shared__ int lh[NTILE];
    for (int i = threadIdx.x; i < NTILE; i += 1024) lh[i] = 0;
    __syncthreads();
    const int stride = NB * 1024;
    for (int e = blockIdx.x * 1024 + threadIdx.x; e < N_EDGES; e += stride)
        atomicAdd(&lh[dst[e] >> 6], 1);
    __syncthreads();
    for (int i = threadIdx.x; i < NTILE; i += 1024)
        histG[i * NB + blockIdx.x] = lh[i];
}

// ---------------------------------------------------------------------------
// 2-level in-place exclusive scan of data[0..K): part -> mid -> final
// K = NTILE*NB = 400128 -> G = 98 blocks of 4096
// ---------------------------------------------------------------------------
__global__ void scan_part(const int* __restrict__ data, int* __restrict__ partial, int K) {
    __shared__ int sh[256];
    const int tid = threadIdx.x, b = blockIdx.x;
    const int i0 = b * 4096 + tid * 16;
    int s = 0;
#pragma unroll
    for (int k = 0; k < 16; ++k) { int i = i0 + k; if (i < K) s += data[i]; }
    sh[tid] = s;
    __syncthreads();
    for (int st = 128; st > 0; st >>= 1) {
        if (tid < st) sh[tid] += sh[tid + st];
        __syncthreads();
    }
    if (tid == 0) partial[b] = sh[0];
}

__global__ __launch_bounds__(512) void scan_mid(int* __restrict__ partial, int G) {
    __shared__ int sh[512];
    const int tid = threadIdx.x;
    int v = (tid < G) ? partial[tid] : 0;
    sh[tid] = v;
    __syncthreads();
    for (int st = 1; st < 512; st <<= 1) {
        int t = (tid >= st) ? sh[tid - st] : 0;
        __syncthreads();
        sh[tid] += t;
        __syncthreads();
    }
    if (tid < G) partial[tid] = sh[tid] - v;        // exclusive
}

__global__ void scan_final(int* __restrict__ data, const int* __restrict__ partial, int K) {
    __shared__ int sh[256];
    const int tid = threadIdx.x, b = blockIdx.x;
    const int i0 = b * 4096 + tid * 16;
    int s = 0;
#pragma unroll
    for (int k = 0; k < 16; ++k) { int i = i0 + k; if (i < K) s += data[i]; }
    sh[tid] = s;
    __syncthreads();
    for (int st = 1; st < 256; st <<= 1) {
        int t = (tid >= st) ? sh[tid - st] : 0;
        __syncthreads();
        sh[tid] += t;
        __syncthreads();
    }
    int run = partial[b] + sh[tid] - s;
#pragma unroll
    for (int k = 0; k < 16; ++k) {
        int i = i0 + k;
        if (i < K) {
            int c = data[i];
            data[i] = run;
            run += c;
        }
    }
}

// ---------------------------------------------------------------------------
// Sort stage 2: place edges into tile-contiguous regions (exact reserved
// ranges from scanned histG, LDS cursors only).
// entry = rel<<23 | (dst&63)<<17 | src   (27 bits)
// ---------------------------------------------------------------------------
__global__ __launch_bounds__(1024) void coarse_place(const int* __restrict__ src,
                                                     const int* __restrict__ dst,
                                                     const int* __restrict__ et,
                                                     const int* __restrict__ histS,
                                                     int* __restrict__ entries) {
    __shared__ int cur[NTILE];
    for (int i = threadIdx.x; i < NTILE; i += 1024)
        cur[i] = histS[i * NB + blockIdx.x];
    __syncthreads();
    const int stride = NB * 1024;
    for (int e = blockIdx.x * 1024 + threadIdx.x; e < N_EDGES; e += stride) {
        int d = dst[e];
        int pos = atomicAdd(&cur[d >> 6], 1);
        entries[pos] = (et[e] << 23) | ((d & 63) << 17) | src[e];
    }
}

// ---------------------------------------------------------------------------
// Sort stage 3: one block per tile; bin edges by rel (per-wave LDS counters,
// exact per-wave bases -> no cross-wave contention). Emits perm + off.
// perm entry = (dst&63)<<17 | src
// ---------------------------------------------------------------------------
__global__ __launch_bounds__(256) void fine_sort(const int* __restrict__ entries,
                                                 const int* __restrict__ histS,
                                                 int* __restrict__ perm,
                                                 int* __restrict__ off) {
    __shared__ int cnt[4][16];
    __shared__ int base[4][16];
    const int tid = threadIdx.x, b = blockIdx.x;
    const int wid = tid >> 6;
    const int start = histS[b * NB];
    const int end = (b + 1 < NTILE) ? histS[(b + 1) * NB] : N_EDGES;

    if (tid < 64) ((int*)cnt)[tid] = 0;
    __syncthreads();
    for (int i = start + tid; i < end; i += 256)
        atomicAdd(&cnt[wid][entries[i] >> 23], 1);
    __syncthreads();
    if (tid == 0) {
        int run = start;
        for (int r = 0; r < NUM_RELS; ++r) {
            off[b * NUM_RELS + r] = run;
            for (int w = 0; w < 4; ++w) { base[w][r] = run; run += cnt[w][r]; }
        }
    }
    if (b == 0 && tid == 64) off[NSEG] = N_EDGES;
    __syncthreads();
    if (tid < 64) ((int*)cnt)[tid] = 0;
    __syncthreads();
    for (int i = start + tid; i < end; i += 256) {
        int en = entries[i];
        int r = en >> 23;
        int p = atomicAdd(&cnt[wid][r], 1);
        perm[base[wid][r] + p] = en & 0x7FFFFF;
    }
}

// ---------------------------------------------------------------------------
// Fused aggregate+transform. One block = 64 dst nodes. For each rel:
//   agg[dl][k] += x_bf16[src][k]  (LDS fp32 atomics; lane l -> cols l, l+64
//   so banks are 2-way aliased = free), then MFMA agg x W_r accumulating in
//   registers across all 16 rels. Single bias-fused fp32 store at the end.
// aggF row stride 132 floats -> row-to-row bank offset 4 (spreads frag reads).
// ---------------------------------------------------------------------------
__global__ __launch_bounds__(256, 4) void rgcn_tile(const unsigned short* __restrict__ xb,
                                                    const unsigned short* __restrict__ Bt,
                                                    const int* __restrict__ off,
                                                    const int* __restrict__ perm,
                                                    const float* __restrict__ bias,
                                                    float* __restrict__ out) {
    __shared__ float aggF[64 * 132];   // 33792 B -> 4 blocks/CU
    const int tile = blockIdx.x;
    const int d0 = tile * 64;
    const int tid = threadIdx.x;
    const int wid = tid >> 6;
    const int lane = tid & 63;
    const int ml = lane & 15, kgrp = lane >> 4;
    const int n0 = wid * 32;           // this wave's out-feat range (32 wide)

    v4f acc[4][2];
#pragma unroll
    for (int i = 0; i < 4; ++i)
#pragma unroll
        for (int j = 0; j < 2; ++j)
            acc[i][j] = (v4f){0.f, 0.f, 0.f, 0.f};

    for (int r = 0; r < NUM_RELS; ++r) {
        for (int i = tid; i < 64 * 132; i += 256) aggF[i] = 0.f;
        __syncthreads();

        const int seg = tile * NUM_RELS + r;
        const int e0 = off[seg], e1 = off[seg + 1];
        int e = e0 + wid;
        for (; e + 12 < e1; e += 16) {
            const int p0 = perm[e], p1 = perm[e + 4], p2 = perm[e + 8], p3 = perm[e + 12];
            const unsigned short* x0 = xb + (size_t)(p0 & 0x1FFFF) * 128;
            const unsigned short* x1 = xb + (size_t)(p1 & 0x1FFFF) * 128;
            const unsigned short* x2 = xb + (size_t)(p2 & 0x1FFFF) * 128;
            const unsigned short* x3 = xb + (size_t)(p3 & 0x1FFFF) * 128;
            unsigned short a0 = x0[lane], b0 = x0[64 + lane];
            unsigned short a1 = x1[lane], b1 = x1[64 + lane];
            unsigned short a2 = x2[lane], b2 = x2[64 + lane];
            unsigned short a3 = x3[lane], b3 = x3[64 + lane];
            float* r0 = &aggF[(p0 >> 17) * 132];
            float* r1 = &aggF[(p1 >> 17) * 132];
            float* r2 = &aggF[(p2 >> 17) * 132];
            float* r3 = &aggF[(p3 >> 17) * 132];
            atomicAdd(r0 + lane, bf2f(a0)); atomicAdd(r0 + 64 + lane, bf2f(b0));
            atomicAdd(r1 + lane, bf2f(a1)); atomicAdd(r1 + 64 + lane, bf2f(b1));
            atomicAdd(r2 + lane, bf2f(a2)); atomicAdd(r2 + 64 + lane, bf2f(b2));
            atomicAdd(r3 + lane, bf2f(a3)); atomicAdd(r3 + 64 + lane, bf2f(b3));
        }
        for (; e < e1; e += 4) {
            const int p = perm[e];
            const unsigned short* xp = xb + (size_t)(p & 0x1FFFF) * 128;
            unsigned short a = xp[lane], b = xp[64 + lane];
            float* rw = &aggF[(p >> 17) * 132];
            atomicAdd(rw + lane, bf2f(a));
            atomicAdd(rw + 64 + lane, bf2f(b));
        }
        __syncthreads();

        const unsigned short* Wr = Bt + (size_t)r * 128 * 128;
#pragma unroll
        for (int kb = 0; kb < 4; ++kb) {
            const int k0 = kb * 32 + kgrp * 8;
            short8 af[4];
#pragma unroll
            for (int tm = 0; tm < 4; ++tm) {
                const float* ap = &aggF[(tm * 16 + ml) * 132 + k0];
                const float4 v0 = *reinterpret_cast<const float4*>(ap);
                const float4 v1 = *reinterpret_cast<const float4*>(ap + 4);
                union { short8 s; unsigned short u[8]; } t;
                t.u[0] = f2bf_rne(v0.x); t.u[1] = f2bf_rne(v0.y);
                t.u[2] = f2bf_rne(v0.z); t.u[3] = f2bf_rne(v0.w);
                t.u[4] = f2bf_rne(v1.x); t.u[5] = f2bf_rne(v1.y);
                t.u[6] = f2bf_rne(v1.z); t.u[7] = f2bf_rne(v1.w);
                af[tm] = t.s;
            }
            short8 bfr[2];
#pragma unroll
            for (int tn = 0; tn < 2; ++tn)
                bfr[tn] = *reinterpret_cast<const short8*>(Wr + (n0 + tn * 16 + ml) * 128 + k0);
#pragma unroll
            for (int tm = 0; tm < 4; ++tm)
#pragma unroll
                for (int tn = 0; tn < 2; ++tn)
                    acc[tm][tn] = __builtin_amdgcn_mfma_f32_16x16x32_bf16(af[tm], bfr[tn], acc[tm][tn], 0, 0, 0);
        }
        __syncthreads();
    }

    // Epilogue: C/D layout col=lane&15, row=(lane>>4)*4+reg  [verified m89/m91]
    const float b0 = bias[n0 + ml];
    const float b1 = bias[n0 + 16 + ml];
#pragma unroll
    for (int tm = 0; tm < 4; ++tm)
#pragma unroll
        for (int rr = 0; rr < 4; ++rr) {
            const int d = d0 + tm * 16 + kgrp * 4 + rr;
            if (d < N_NODES) {
                out[(size_t)d * OUT_FEAT + n0 + ml]      = acc[tm][0][rr] + b0;
                out[(size_t)d * OUT_FEAT + n0 + 16 + ml] = acc[tm][1][rr] + b1;
            }
        }
}

static inline size_t align256(size_t a) { return (a + 255) & ~(size_t)255; }

extern "C" void kernel_launch(void* const* d_in, const int* in_sizes, int n_in,
                              void* d_out, int out_size, void* d_ws, size_t ws_size,
                              hipStream_t stream) {
    const float* x      = (const float*)d_in[0];
    const float* weight = (const float*)d_in[1];
    const float* w_comp = (const float*)d_in[2];
    const float* h_bias = (const float*)d_in[3];
    const int*   src    = (const int*)d_in[4];
    const int*   dst    = (const int*)d_in[5];
    const int*   etypes = (const int*)d_in[6];
    float* out = (float*)d_out;

    // Workspace layout (~54 MB total; earlier rounds prove ws >= 200 MB)
    char* w = (char*)d_ws;
    size_t a = 0;
    unsigned short* Bt      = (unsigned short*)(w + a); a = align256(a + 512 * 1024);
    unsigned short* xb      = (unsigned short*)(w + a); a = align256(a + (size_t)M_PAD * 128 * 2);
    int*            perm    = (int*)(w + a); a = align256(a + (size_t)N_EDGES * 4);
    int*            entries = (int*)(w + a); a = align256(a + (size_t)N_EDGES * 4);
    int*            off     = (int*)(w + a); a = align256(a + (size_t)(NSEG + 1) * 4);
    int*            histG   = (int*)(w + a); a = align256(a + (size_t)NTILE * NB * 4);
    int*            partial = (int*)(w + a); a = align256(a + 512 * 4);

    const int K2 = NTILE * NB;                 // 400128
    const int G2 = (K2 + 4095) / 4096;         // 98

    conv_x<<<12512, 256, 0, stream>>>(x, xb);
    build_w<<<1024, 256, 0, stream>>>(weight, w_comp, Bt);

    coarse_hist<<<NB, 1024, 0, stream>>>(dst, histG);
    scan_part<<<G2, 256, 0, stream>>>(histG, partial, K2);
    scan_mid<<<1, 512, 0, stream>>>(partial, G2);
    scan_final<<<G2, 256, 0, stream>>>(histG, partial, K2);
    coarse_place<<<NB, 1024, 0, stream>>>(src, dst, etypes, histG, entries);
    fine_sort<<<NTILE, 256, 0, stream>>>(entries, histG, perm, off);

    rgcn_tile<<<NTILE, 256, 0, stream>>>(xb, Bt, off, perm, h_bias, out);
}

// Round 7
// 552.550 us; speedup vs baseline: 5.0193x; 5.0193x over previous
//
#include <hip/hip_runtime.h>
#include <hip/hip_bf16.h>
#include <stdint.h>

#define N_NODES   100000
#define N_EDGES   3200000
#define IN_FEAT   128
#define OUT_FEAT  128
#define NUM_RELS  16
#define NUM_BASES 8
#define M_PAD     100096      // 782 * 128
#define NBKT      391         // coarse buckets per chunk = ceil(100000/256)
#define NB        256         // blocks in coarse hist/place (must match both)

using short8 = __attribute__((ext_vector_type(8))) short;
using v4f    = __attribute__((ext_vector_type(4))) float;

__device__ inline unsigned short f2bf_rne(float f) {
    __hip_bfloat16 h = __float2bfloat16(f);
    return *reinterpret_cast<unsigned short*>(&h);
}
__device__ inline float bf2f(unsigned short u) {
    union { uint32_t i; float f; } x;
    x.i = ((uint32_t)u) << 16;
    return x.f;
}

// ---------------------------------------------------------------------------
// x fp32 -> bf16, zero-padded to M_PAD rows
// ---------------------------------------------------------------------------
__global__ void conv_x(const float* __restrict__ x, unsigned short* __restrict__ xb) {
    int id = blockIdx.x * 256 + threadIdx.x;
    int base = id * 4;
    ushort4 o;
    if (base < N_NODES * IN_FEAT) {
        const float4 v = reinterpret_cast<const float4*>(x)[id];
        o.x = f2bf_rne(v.x); o.y = f2bf_rne(v.y);
        o.z = f2bf_rne(v.z); o.w = f2bf_rne(v.w);
    } else {
        o.x = o.y = o.z = o.w = 0;
    }
    reinterpret_cast<ushort4*>(xb)[id] = o;
}

// ---------------------------------------------------------------------------
// Bt[n][k] = sum_b w_comp[r][b] * weight[b][k][o], n = r*128+o (bf16)
// ---------------------------------------------------------------------------
__global__ void build_w(const float* __restrict__ weight,
                        const float* __restrict__ w_comp,
                        unsigned short* __restrict__ Bt) {
    int id = blockIdx.x * 256 + threadIdx.x;
    int n = id >> 7;
    int k = id & 127;
    int r = n >> 7;
    int o = n & 127;
    float acc = 0.f;
#pragma unroll
    for (int b = 0; b < NUM_BASES; ++b)
        acc += w_comp[r * NUM_BASES + b] * weight[(b * IN_FEAT + k) * OUT_FEAT + o];
    Bt[id] = f2bf_rne(acc);
}

// ---------------------------------------------------------------------------
// Two-level sort by (chunk, dst). Coarse bucket b = chunk*NBKT + (dst>>8).
// Phase 1: per-block LDS histogram -> histG[b*NB + nb]  (no global atomics)
// ---------------------------------------------------------------------------
__global__ __launch_bounds__(1024) void coarse_hist(const int* __restrict__ dst,
                                                    const int* __restrict__ et,
                                                    int* __restrict__ histG,
                                                    int lg, int nbuck) {
    extern __shared__ int lh[];
    for (int i = threadIdx.x; i < nbuck; i += 1024) lh[i] = 0;
    __syncthreads();
    const int stride = NB * 1024;
    for (int e = blockIdx.x * 1024 + threadIdx.x; e < N_EDGES; e += stride)
        atomicAdd(&lh[(et[e] >> lg) * NBKT + (dst[e] >> 8)], 1);
    __syncthreads();
    for (int i = threadIdx.x; i < nbuck; i += 1024)
        histG[i * NB + blockIdx.x] = lh[i];
}

// ---------------------------------------------------------------------------
// 2-level in-place exclusive scan of data[0..K): part -> mid -> final
// ---------------------------------------------------------------------------
__global__ void scan_part(const int* __restrict__ data, int* __restrict__ partial, int K) {
    __shared__ int sh[256];
    const int tid = threadIdx.x, b = blockIdx.x;
    const int i0 = b * 4096 + tid * 16;
    int s = 0;
#pragma unroll
    for (int k = 0; k < 16; ++k) { int i = i0 + k; if (i < K) s += data[i]; }
    sh[tid] = s;
    __syncthreads();
    for (int st = 128; st > 0; st >>= 1) {
        if (tid < st) sh[tid] += sh[tid + st];
        __syncthreads();
    }
    if (tid == 0) partial[b] = sh[0];
}

__global__ __launch_bounds__(512) void scan_mid(int* __restrict__ partial, int G) {
    __shared__ int sh[512];
    const int tid = threadIdx.x;
    int v = (tid < G) ? partial[tid] : 0;
    sh[tid] = v;
    __syncthreads();
    for (int st = 1; st < 512; st <<= 1) {
        int t = (tid >= st) ? sh[tid - st] : 0;
        __syncthreads();
        sh[tid] += t;
        __syncthreads();
    }
    if (tid < G) partial[tid] = sh[tid] - v;        // exclusive
}

// in-place: each element read before overwrite by the same thread
__global__ void scan_final(int* __restrict__ data, const int* __restrict__ partial, int K) {
    __shared__ int sh[256];
    const int tid = threadIdx.x, b = blockIdx.x;
    const int i0 = b * 4096 + tid * 16;
    int s = 0;
#pragma unroll
    for (int k = 0; k < 16; ++k) { int i = i0 + k; if (i < K) s += data[i]; }
    sh[tid] = s;
    __syncthreads();
    for (int st = 1; st < 256; st <<= 1) {
        int t = (tid >= st) ? sh[tid - st] : 0;
        __syncthreads();
        sh[tid] += t;
        __syncthreads();
    }
    int run = partial[b] + sh[tid] - s;
#pragma unroll
    for (int k = 0; k < 16; ++k) {
        int i = i0 + k;
        if (i < K) {
            int c = data[i];
            data[i] = run;
            run += c;
        }
    }
}

// ---------------------------------------------------------------------------
// Phase 2: place edges into bucket-contiguous regions using exact reserved
// ranges (histS = scanned histG). LDS cursors only; writes are ~16-entry runs.
// entry = (dst&255)<<21 | src<<4 | rl   (29 bits)
// ---------------------------------------------------------------------------
__global__ __launch_bounds__(1024) void coarse_place(const int* __restrict__ src,
                                                     const int* __restrict__ dst,
                                                     const int* __restrict__ et,
                                                     const int* __restrict__ histS,
                                                     int* __restrict__ entries,
                                                     int lg, int RCm1, int nbuck) {
    extern __shared__ int cur[];
    for (int i = threadIdx.x; i < nbuck; i += 1024)
        cur[i] = histS[i * NB + blockIdx.x];
    __syncthreads();
    const int stride = NB * 1024;
    for (int e = blockIdx.x * 1024 + threadIdx.x; e < N_EDGES; e += stride) {
        int t = et[e], d = dst[e];
        int b = (t >> lg) * NBKT + (d >> 8);
        int pos = atomicAdd(&cur[b], 1);
        entries[pos] = ((d & 255) << 21) | (src[e] << 4) | (t & RCm1);
    }
}

// ---------------------------------------------------------------------------
// Phase 3: one block per bucket; counting sort by dst-low-8 in LDS (2-pass,
// no capacity limit). Emits coalesced perm runs AND per-node off[] directly.
// ---------------------------------------------------------------------------
__global__ __launch_bounds__(256) void fine_sort(const int* __restrict__ entries,
                                                 const int* __restrict__ histS,
                                                 int* __restrict__ perm,
                                                 int* __restrict__ off,
                                                 int nbuck, int nch) {
    __shared__ int cnt[256];
    __shared__ int bs[256];
    const int tid = threadIdx.x, b = blockIdx.x;
    const int start = histS[b * NB];
    const int end   = (b + 1 < nbuck) ? histS[(b + 1) * NB] : N_EDGES;

    cnt[tid] = 0;
    __syncthreads();
    for (int i = start + tid; i < end; i += 256)
        atomicAdd(&cnt[entries[i] >> 21], 1);
    __syncthreads();

    int v = cnt[tid];
    bs[tid] = v;
    __syncthreads();
    for (int st = 1; st < 256; st <<= 1) {
        int t = (tid >= st) ? bs[tid - st] : 0;
        __syncthreads();
        bs[tid] += t;
        __syncthreads();
    }
    const int excl = bs[tid] - v;      // exclusive prefix among dlow

    const int c  = b / NBKT;
    const int dh = b % NBKT;
    const int d  = dh * 256 + tid;
    if (d < N_NODES) off[c * N_NODES + d] = start + excl;
    if (b == nbuck - 1 && tid == 0) off[nch * N_NODES] = N_EDGES;

    __syncthreads();
    cnt[tid] = excl;                   // cursor
    __syncthreads();
    for (int i = start + tid; i < end; i += 256) {
        int en = entries[i];
        int p = atomicAdd(&cnt[en >> 21], 1);
        perm[start + p] = en & 0x1FFFFF;   // (src<<4)|rl
    }
}

// ---------------------------------------------------------------------------
// GEMM, m97-style: 128x128 tile, K=128 via global_load_lds(16B), XOR-swizzled
// ---------------------------------------------------------------------------
__global__ __launch_bounds__(256, 2) void gemm_h(const unsigned short* __restrict__ xb,
                                                 const unsigned short* __restrict__ Bt,
                                                 unsigned short* __restrict__ h2,
                                                 int c, int RC) {
    __shared__ unsigned short lA[128 * 128];
    __shared__ unsigned short lB[128 * 128];

    const int mb = blockIdx.x;
    const int rl = blockIdx.y;
    const int r  = c * RC + rl;
    const int tid  = threadIdx.x;
    const int wid  = tid >> 6;
    const int lane = tid & 63;

    const unsigned short* gA = xb + (size_t)mb * 128 * IN_FEAT;
    const unsigned short* gB = Bt + (size_t)r  * 128 * IN_FEAT;

#pragma unroll
    for (int it = 0; it < 8; ++it) {
        int sbase = it * 256 + wid * 64;
        int s = sbase + lane;
        int row = s >> 4;
        int cc = (s & 15) ^ (row & 15);
        __builtin_amdgcn_global_load_lds(
            (const __attribute__((address_space(1))) void*)(gA + row * 128 + cc * 8),
            (__attribute__((address_space(3))) void*)(&lA[sbase * 8]), 16, 0, 0);
    }
#pragma unroll
    for (int it = 0; it < 8; ++it) {
        int sbase = it * 256 + wid * 64;
        int s = sbase + lane;
        int row = s >> 4;
        int cc = (s & 15) ^ (row & 15);
        __builtin_amdgcn_global_load_lds(
            (const __attribute__((address_space(1))) void*)(gB + row * 128 + cc * 8),
            (__attribute__((address_space(3))) void*)(&lB[sbase * 8]), 16, 0, 0);
    }
    __syncthreads();

    const int wm = wid >> 1, wn = wid & 1;
    const int ml = lane & 15, kgrp = lane >> 4;

    v4f acc[4][4];
#pragma unroll
    for (int i = 0; i < 4; ++i)
#pragma unroll
        for (int j = 0; j < 4; ++j)
            acc[i][j] = (v4f){0.f, 0.f, 0.f, 0.f};

#pragma unroll
    for (int kb = 0; kb < 4; ++kb) {
        const int cc = kb * 4 + kgrp;
        short8 af[4], bfr[4];
#pragma unroll
        for (int tm = 0; tm < 4; ++tm) {
            int rA = wm * 64 + tm * 16 + ml;
            af[tm] = *reinterpret_cast<const short8*>(&lA[(rA * 16 + (cc ^ (rA & 15))) * 8]);
        }
#pragma unroll
        for (int tn = 0; tn < 4; ++tn) {
            int rB = wn * 64 + tn * 16 + ml;
            bfr[tn] = *reinterpret_cast<const short8*>(&lB[(rB * 16 + (cc ^ (rB & 15))) * 8]);
        }
#pragma unroll
        for (int tm = 0; tm < 4; ++tm)
#pragma unroll
            for (int tn = 0; tn < 4; ++tn)
                acc[tm][tn] = __builtin_amdgcn_mfma_f32_16x16x32_bf16(af[tm], bfr[tn], acc[tm][tn], 0, 0, 0);
    }

    const int ncols = RC * 128;
    const int row0 = mb * 128 + wm * 64;
    const int col0 = rl * 128 + wn * 64;
#pragma unroll
    for (int tm = 0; tm < 4; ++tm)
#pragma unroll
        for (int rr = 0; rr < 4; ++rr) {
            int row = row0 + tm * 16 + kgrp * 4 + rr;
            size_t rb = (size_t)row * ncols;
#pragma unroll
            for (int tn = 0; tn < 4; ++tn) {
                int col = col0 + tn * 16 + ml;
                h2[rb + col] = f2bf_rne(acc[tm][tn][rr]);
            }
        }
}

// ---------------------------------------------------------------------------
// Gather: one wave per (chunk, node) segment; unroll x8 for MLP. RC is a
// template param so the h2 row stride is a compile-time shift (no v_mul in
// the address chain).
// ---------------------------------------------------------------------------
template <int RCT>
__global__ void gatherT(const int* __restrict__ off, const int* __restrict__ perm,
                        const unsigned short* __restrict__ h2,
                        const float* __restrict__ bias,
                        float* __restrict__ out, int c) {
    const int d = blockIdx.x * 4 + (threadIdx.x >> 6);
    const int lane = threadIdx.x & 63;
    const int kb = c * N_NODES + d;
    const int e0 = off[kb], e1 = off[kb + 1];
    const unsigned short* hb = h2 + lane * 2;   // lane-fixed byte offset
    float2 acc = make_float2(0.f, 0.f);
    int e = e0;
    for (; e + 8 <= e1; e += 8) {
        int p[8];
#pragma unroll
        for (int j = 0; j < 8; ++j) p[j] = perm[e + j];
        ushort2 v[8];
#pragma unroll
        for (int j = 0; j < 8; ++j)
            v[j] = *reinterpret_cast<const ushort2*>(
                hb + ((size_t)(p[j] >> 4) * RCT + (p[j] & 15)) * 128);
#pragma unroll
        for (int j = 0; j < 8; ++j) {
            acc.x += bf2f(v[j].x);
            acc.y += bf2f(v[j].y);
        }
    }
    for (; e + 2 <= e1; e += 2) {
        int p0 = perm[e], p1 = perm[e + 1];
        ushort2 v0 = *reinterpret_cast<const ushort2*>(
            hb + ((size_t)(p0 >> 4) * RCT + (p0 & 15)) * 128);
        ushort2 v1 = *reinterpret_cast<const ushort2*>(
            hb + ((size_t)(p1 >> 4) * RCT + (p1 & 15)) * 128);
        acc.x += bf2f(v0.x) + bf2f(v1.x);
        acc.y += bf2f(v0.y) + bf2f(v1.y);
    }
    for (; e < e1; ++e) {
        int p = perm[e];
        ushort2 v = *reinterpret_cast<const ushort2*>(
            hb + ((size_t)(p >> 4) * RCT + (p & 15)) * 128);
        acc.x += bf2f(v.x);
        acc.y += bf2f(v.y);
    }
    float* po = out + (size_t)d * OUT_FEAT + lane * 2;
    if (c == 0) {
        acc.x += bias[lane * 2];
        acc.y += bias[lane * 2 + 1];
    } else {
        float2 prev = *reinterpret_cast<const float2*>(po);
        acc.x += prev.x;
        acc.y += prev.y;
    }
    *reinterpret_cast<float2*>(po) = acc;
}

static inline size_t align256(size_t a) { return (a + 255) & ~(size_t)255; }

extern "C" void kernel_launch(void* const* d_in, const int* in_sizes, int n_in,
                              void* d_out, int out_size, void* d_ws, size_t ws_size,
                              hipStream_t stream) {
    const float* x      = (const float*)d_in[0];
    const float* weight = (const float*)d_in[1];
    const float* w_comp = (const float*)d_in[2];
    const float* h_bias = (const float*)d_in[3];
    const int*   src    = (const int*)d_in[4];
    const int*   dst    = (const int*)d_in[5];
    const int*   etypes = (const int*)d_in[6];
    float* out = (float*)d_out;

    const size_t per_rel = (size_t)M_PAD * 128 * 2;   // 25,624,576 B

    // Choose RC and lay out workspace. entries/histG alias h2 (dead before gemm).
    int RC = 16, lg = 4;
    size_t perm_o = 0, off_o = 0, part_o = 0, h2_o = 0;
    for (;;) {
        int nch = NUM_RELS / RC;
        size_t a = 512 * 1024;                                   // Bt
        a = align256(a + per_rel);                               // xb
        perm_o = a; a = align256(a + (size_t)N_EDGES * 4);       // perm
        off_o  = a; a = align256(a + ((size_t)nch * N_NODES + 1) * 4);
        part_o = a; a = align256(a + 512 * 4);                   // scan partials
        h2_o   = a; a += per_rel * (size_t)RC;                   // h2 (>= 25.6MB)
        if (a <= ws_size || RC == 1) break;
        RC >>= 1; lg -= 1;
    }
    const int nch = NUM_RELS / RC;
    const int nbuck = nch * NBKT;
    const int K2 = nbuck * NB;
    const int G2 = (K2 + 4095) / 4096;

    char* w = (char*)d_ws;
    unsigned short* Bt      = (unsigned short*)(w);
    unsigned short* xb      = (unsigned short*)(w + 512 * 1024);
    int*            perm    = (int*)(w + perm_o);
    int*            off     = (int*)(w + off_o);
    int*            partial = (int*)(w + part_o);
    unsigned short* h2      = (unsigned short*)(w + h2_o);
    int*            entries = (int*)(w + h2_o);                  // alias h2[0..12.8MB)
    int*            histG   = (int*)(w + h2_o + 13 * 1024 * 1024); // alias h2[13MB..)

    conv_x<<<12512, 256, 0, stream>>>(x, xb);
    build_w<<<1024, 256, 0, stream>>>(weight, w_comp, Bt);

    coarse_hist<<<NB, 1024, nbuck * 4, stream>>>(dst, etypes, histG, lg, nbuck);
    scan_part<<<G2, 256, 0, stream>>>(histG, partial, K2);
    scan_mid<<<1, 512, 0, stream>>>(partial, G2);
    scan_final<<<G2, 256, 0, stream>>>(histG, partial, K2);
    coarse_place<<<NB, 1024, nbuck * 4, stream>>>(src, dst, etypes, histG, entries,
                                                  lg, RC - 1, nbuck);
    fine_sort<<<nbuck, 256, 0, stream>>>(entries, histG, perm, off, nbuck, nch);

    for (int c = 0; c < nch; ++c) {
        gemm_h<<<dim3(782, RC), 256, 0, stream>>>(xb, Bt, h2, c, RC);
        switch (RC) {
            case 16: gatherT<16><<<25000, 256, 0, stream>>>(off, perm, h2, h_bias, out, c); break;
            case 8:  gatherT<8> <<<25000, 256, 0, stream>>>(off, perm, h2, h_bias, out, c); break;
            case 4:  gatherT<4> <<<25000, 256, 0, stream>>>(off, perm, h2, h_bias, out, c); break;
            case 2:  gatherT<2> <<<25000, 256, 0, stream>>>(off, perm, h2, h_bias, out, c); break;
            default: gatherT<1> <<<25000, 256, 0, stream>>>(off, perm, h2, h_bias, out, c); break;
        }
    }
}